// Round 4
// baseline (95.043 us; speedup 1.0000x reference)
//
#include <hip/hip_runtime.h>
#include <math.h>

// Problem constants (fixed shapes from reference)
#define IN_CH   8
#define OUT_CH  16
#define DIM     32
#define PDIM    34          // padded (pad=1 each side)
#define NBASES  8           // GRID_SIZE + SPLINE_ORDER
#define NF      216         // IN_CH * 27
#define LTOT    32768       // 32^3
#define TPAD    12          // 9 real values (silu + 8 bases) padded to 12
#define KVOX    96          // 8 channels * TPAD halves per voxel

typedef _Float16 half8 __attribute__((ext_vector_type(8)));
typedef float    f32x4 __attribute__((ext_vector_type(4)));

// knot j of the (uniform) extended grid: (j-3)*h + lo, h=0.4, lo=-1
__device__ __forceinline__ float knot(int j) {
    return (float)(j - 3) * 0.4f + (-1.0f);
}

// Cox-de Boor recursion, exactly mirroring the reference (order 3, 12 knots).
__device__ __forceinline__ void eval_bases(float v, float b[11]) {
    #pragma unroll
    for (int j = 0; j < 11; ++j)
        b[j] = (v >= knot(j) && v < knot(j + 1)) ? 1.0f : 0.0f;
    #pragma unroll
    for (int k = 1; k <= 3; ++k) {
        #pragma unroll
        for (int j = 0; j + k < 11; ++j) {
            float denl = knot(j + k)     - knot(j);
            float denr = knot(j + k + 1) - knot(j + 1);
            b[j] = (v - knot(j)) / denl * b[j]
                 + (knot(j + k + 1) - v) / denr * b[j + 1];
        }
    }
}

__device__ __forceinline__ float silu(float v) {
    return v / (1.0f + expf(-v));
}

// ---- Stage 1b: weights Wt[(tap*3+q)*16 + o][32] fp16 ----------------------
// k = q*32 + kl (0..95), c = k/12, t = k%12; t==0 -> base, 1..8 -> spline*scaler.
__global__ void prep_weights(const float* __restrict__ bw,   // [16][216]
                             const float* __restrict__ sw,   // [16][216][8]
                             const float* __restrict__ sc,   // [16][216]
                             _Float16* __restrict__ Wt) {
    int id = blockIdx.x * blockDim.x + threadIdx.x;
    if (id >= 27 * 3 * 16 * 32) return;
    int kl  = id & 31;
    int o   = (id >> 5) & 15;
    int tq  = id >> 9;          // tap*3 + q
    int q   = tq % 3;
    int tap = tq / 3;
    int k = q * 32 + kl;        // 0..95
    int cch = k / TPAD, t = k % TPAD;
    float val = 0.0f;
    if (t < 9) {
        int wi = o * NF + (cch * 27 + tap);
        val = (t == 0) ? bw[wi] : sw[(size_t)wi * NBASES + (t - 1)] * sc[wi];
    }
    Wt[id] = (_Float16)val;
}

// ---- Fused conv: compute halo spline-field into LDS, then implicit-GEMM ----
// Block: 256 thr = 4 waves. Output tile: 16(x) x 2(y) x 2(z) positions.
// LDS: halo field 18 x 4 x 4 voxels * 8ch * 12 halves = 55,296 B.
__global__ __launch_bounds__(256) void conv_fused(const float* __restrict__ x,
                                                  const _Float16* __restrict__ Wt,
                                                  float* __restrict__ out) {
    __shared__ __align__(16) _Float16 lf[288 * KVOX];   // 27648 halves
    int bx = blockIdx.x;
    int x0 = (bx & 1) * 16;
    int y0 = ((bx >> 1) & 15) * 2;
    int z0 = (bx >> 5) * 2;
    int tid = threadIdx.x;

    // ---- staging: 288 voxels x 8 ch = 2304 = 9 * 256 -----------------------
    #pragma unroll
    for (int it = 0; it < 9; ++it) {
        int i = tid + it * 256;
        int c = i / 288;
        int v = i % 288;            // (lz*4 + ly)*18 + lx
        int lx = v % 18;
        int t2 = v / 18;
        int ly = t2 & 3, lz = t2 >> 2;
        int xp = x0 + lx, yp = y0 + ly, zp = z0 + lz;   // padded coords
        float val = 0.0f;
        if (xp >= 1 && xp <= DIM && yp >= 1 && yp <= DIM && zp >= 1 && zp <= DIM)
            val = x[((c * DIM + (zp - 1)) * DIM + (yp - 1)) * DIM + (xp - 1)];
        float b[11];
        eval_bases(val, b);
        __align__(8) _Float16 h[TPAD];
        h[0] = (_Float16)silu(val);
        #pragma unroll
        for (int j = 0; j < NBASES; ++j) h[1 + j] = (_Float16)b[j];
        h[9] = (_Float16)0.f; h[10] = (_Float16)0.f; h[11] = (_Float16)0.f;
        uint2* d = (uint2*)(lf + (size_t)v * KVOX + c * TPAD);  // 24 B, 8-aligned
        d[0] = *(uint2*)&h[0];
        d[1] = *(uint2*)&h[4];
        d[2] = *(uint2*)&h[8];
    }
    __syncthreads();

    // ---- MFMA phase (identical to verified R3 layout) ----------------------
    int lane = tid & 63;
    int w    = tid >> 6;
    int yw = w & 1, zw = w >> 1;
    int po = lane & 15;      // a: out-channel row; b: position col
    int kq = lane >> 4;      // K sub-chunk (8 halves each)
    f32x4 acc = {0.f, 0.f, 0.f, 0.f};

    #pragma unroll
    for (int kd = 0; kd < 3; ++kd) {
        #pragma unroll
        for (int kh = 0; kh < 3; ++kh) {
            const _Float16* lrow = lf + ((zw + kd) * 4 + (yw + kh)) * (18 * KVOX);
            #pragma unroll
            for (int kw = 0; kw < 3; ++kw) {
                #pragma unroll
                for (int q = 0; q < 3; ++q) {
                    int tap = (kd * 3 + kh) * 3 + kw;
                    half8 a = *(const half8*)(Wt + ((tap * 3 + q) * 16 + po) * 32 + kq * 8);
                    half8 b = *(const half8*)(lrow + (po + kw) * KVOX + q * 32 + kq * 8);
                    acc = __builtin_amdgcn_mfma_f32_16x16x32_f16(a, b, acc, 0, 0, 0);
                }
            }
        }
    }

    int pos = ((z0 + zw) * 32 + (y0 + yw)) * 32 + x0 + po;
    #pragma unroll
    for (int r = 0; r < 4; ++r)
        out[(size_t)(kq * 4 + r) * LTOT + pos] = acc[r];
}

// ---------------- Fallback: fully fused (no workspace needed) ---------------
__global__ __launch_bounds__(64) void fused_kernel(const float* __restrict__ x,
                                                   const float* __restrict__ bw,
                                                   const float* __restrict__ sw,
                                                   const float* __restrict__ sc,
                                                   float* __restrict__ out) {
    int p = blockIdx.x * 64 + threadIdx.x;
    int xo = p & 31;
    int yo = (p >> 5) & 31;
    int zo = p >> 10;
    float acc[OUT_CH];
    #pragma unroll
    for (int o = 0; o < OUT_CH; ++o) acc[o] = 0.0f;
    for (int c = 0; c < IN_CH; ++c)
        for (int kd = 0; kd < 3; ++kd)
            for (int kh = 0; kh < 3; ++kh)
                for (int kw = 0; kw < 3; ++kw) {
                    int zi = zo + kd - 1, yi = yo + kh - 1, xi = xo + kw - 1;
                    float v = 0.0f;
                    if (zi >= 0 && zi < DIM && yi >= 0 && yi < DIM && xi >= 0 && xi < DIM)
                        v = x[((c * DIM + zi) * DIM + yi) * DIM + xi];
                    float b[11];
                    eval_bases(v, b);
                    float s = silu(v);
                    int i = c * 27 + kd * 9 + kh * 3 + kw;
                    #pragma unroll
                    for (int o = 0; o < OUT_CH; ++o) {
                        int wi = o * NF + i;
                        float dot = 0.0f;
                        #pragma unroll
                        for (int j = 0; j < NBASES; ++j)
                            dot += b[j] * sw[(size_t)wi * NBASES + j];
                        acc[o] += s * bw[wi] + sc[wi] * dot;
                    }
                }
    #pragma unroll
    for (int o = 0; o < OUT_CH; ++o)
        out[(size_t)o * LTOT + p] = acc[o];
}

extern "C" void kernel_launch(void* const* d_in, const int* in_sizes, int n_in,
                              void* d_out, int out_size, void* d_ws, size_t ws_size,
                              hipStream_t stream) {
    const float* x  = (const float*)d_in[0];
    const float* bw = (const float*)d_in[1];
    const float* sw = (const float*)d_in[2];
    const float* sc = (const float*)d_in[3];
    float* out = (float*)d_out;

    const size_t W_bytes = (size_t)27 * 3 * 16 * 32 * 2;      // 82,944
    if (ws_size >= W_bytes) {
        _Float16* Wt = (_Float16*)d_ws;
        prep_weights<<<(27 * 3 * 16 * 32 + 255) / 256, 256, 0, stream>>>(bw, sw, sc, Wt);
        conv_fused<<<512, 256, 0, stream>>>(x, Wt, out);
    } else {
        fused_kernel<<<512, 64, 0, stream>>>(x, bw, sw, sc, out);
    }
}

// Round 5
// 78.407 us; speedup vs baseline: 1.2122x; 1.2122x over previous
//
#include <hip/hip_runtime.h>
#include <math.h>

// Problem constants (fixed shapes from reference)
#define IN_CH   8
#define OUT_CH  16
#define DIM     32
#define PDIM    34          // padded (pad=1 each side)
#define NBASES  8           // GRID_SIZE + SPLINE_ORDER
#define NF      216         // IN_CH * 27
#define LTOT    32768       // 32^3
#define TPAD    12          // 9 real values (silu + 8 bases) padded to 12
#define KVOX    96          // 8 channels * TPAD halves per voxel

typedef _Float16 half8 __attribute__((ext_vector_type(8)));
typedef float    f32x4 __attribute__((ext_vector_type(4)));

// knot j of the (uniform) extended grid: (j-3)*h + lo, h=0.4, lo=-1
__device__ __forceinline__ float knot(int j) {
    return (float)(j - 3) * 0.4f + (-1.0f);
}

// Cox-de Boor recursion, mirroring the reference (order 3, 12 knots).
// Divisions by knot-difference CONSTANTS rewritten as multiplies by
// compile-time-folded reciprocals: x/0.4 etc. cannot be strength-reduced by
// the compiler under strict IEEE, and cost ~10 instr each (54 of them!).
// 1.0f/(const) folds at compile time; rel err <= 1e-7, absmax unchanged.
__device__ __forceinline__ void eval_bases(float v, float b[11]) {
    #pragma unroll
    for (int j = 0; j < 11; ++j)
        b[j] = (v >= knot(j) && v < knot(j + 1)) ? 1.0f : 0.0f;
    #pragma unroll
    for (int k = 1; k <= 3; ++k) {
        #pragma unroll
        for (int j = 0; j + k < 11; ++j) {
            float rl = 1.0f / (knot(j + k)     - knot(j));      // const-folded
            float rr = 1.0f / (knot(j + k + 1) - knot(j + 1));  // const-folded
            b[j] = (v - knot(j)) * rl * b[j]
                 + (knot(j + k + 1) - v) * rr * b[j + 1];
        }
    }
}

__device__ __forceinline__ float silu(float v) {
    return v / (1.0f + __expf(-v));
}

// ---- Stage 1b: weights Wt[(tap*3+q)*16 + o][32] fp16 ----------------------
// k = q*32 + kl (0..95), c = k/12, t = k%12; t==0 -> base, 1..8 -> spline*scaler.
__global__ void prep_weights(const float* __restrict__ bw,   // [16][216]
                             const float* __restrict__ sw,   // [16][216][8]
                             const float* __restrict__ sc,   // [16][216]
                             _Float16* __restrict__ Wt) {
    int id = blockIdx.x * blockDim.x + threadIdx.x;
    if (id >= 27 * 3 * 16 * 32) return;
    int kl  = id & 31;
    int o   = (id >> 5) & 15;
    int tq  = id >> 9;          // tap*3 + q
    int q   = tq % 3;
    int tap = tq / 3;
    int k = q * 32 + kl;        // 0..95
    int cch = k / TPAD, t = k % TPAD;
    float val = 0.0f;
    if (t < 9) {
        int wi = o * NF + (cch * 27 + tap);
        val = (t == 0) ? bw[wi] : sw[(size_t)wi * NBASES + (t - 1)] * sc[wi];
    }
    Wt[id] = (_Float16)val;
}

// ---- Fused conv: compute halo spline-field into LDS, then implicit-GEMM ----
// Block: 256 thr = 4 waves. Output tile: 16(x) x 2(y) x 2(z) positions.
// LDS: halo field 18 x 4 x 4 voxels * 8ch * 12 halves = 55,296 B (2 blk/CU).
__global__ __launch_bounds__(256) void conv_fused(const float* __restrict__ x,
                                                  const _Float16* __restrict__ Wt,
                                                  float* __restrict__ out) {
    __shared__ __align__(16) _Float16 lf[288 * KVOX];   // 27648 halves
    int bx = blockIdx.x;
    int x0 = (bx & 1) * 16;
    int y0 = ((bx >> 1) & 15) * 2;
    int z0 = (bx >> 5) * 2;
    int tid = threadIdx.x;

    // ---- staging: 288 voxels x 8 ch = 2304 = 9 * 256 -----------------------
    #pragma unroll
    for (int it = 0; it < 9; ++it) {
        int i = tid + it * 256;
        int c = i / 288;
        int v = i % 288;            // (lz*4 + ly)*18 + lx
        int lx = v % 18;
        int t2 = v / 18;
        int ly = t2 & 3, lz = t2 >> 2;
        int xp = x0 + lx, yp = y0 + ly, zp = z0 + lz;   // padded coords
        float val = 0.0f;
        if (xp >= 1 && xp <= DIM && yp >= 1 && yp <= DIM && zp >= 1 && zp <= DIM)
            val = x[((c * DIM + (zp - 1)) * DIM + (yp - 1)) * DIM + (xp - 1)];
        float b[11];
        eval_bases(val, b);
        __align__(8) _Float16 h[TPAD];
        h[0] = (_Float16)silu(val);
        #pragma unroll
        for (int j = 0; j < NBASES; ++j) h[1 + j] = (_Float16)b[j];
        h[9] = (_Float16)0.f; h[10] = (_Float16)0.f; h[11] = (_Float16)0.f;
        uint2* d = (uint2*)(lf + (size_t)v * KVOX + c * TPAD);  // 24 B, 8-aligned
        d[0] = *(uint2*)&h[0];
        d[1] = *(uint2*)&h[4];
        d[2] = *(uint2*)&h[8];
    }
    __syncthreads();

    // ---- MFMA phase (identical to verified R3 layout) ----------------------
    int lane = tid & 63;
    int w    = tid >> 6;
    int yw = w & 1, zw = w >> 1;
    int po = lane & 15;      // a: out-channel row; b: position col
    int kq = lane >> 4;      // K sub-chunk (8 halves each)
    f32x4 acc = {0.f, 0.f, 0.f, 0.f};

    #pragma unroll
    for (int kd = 0; kd < 3; ++kd) {
        #pragma unroll
        for (int kh = 0; kh < 3; ++kh) {
            const _Float16* lrow = lf + ((zw + kd) * 4 + (yw + kh)) * (18 * KVOX);
            #pragma unroll
            for (int kw = 0; kw < 3; ++kw) {
                #pragma unroll
                for (int q = 0; q < 3; ++q) {
                    int tap = (kd * 3 + kh) * 3 + kw;
                    half8 a = *(const half8*)(Wt + ((tap * 3 + q) * 16 + po) * 32 + kq * 8);
                    half8 b = *(const half8*)(lrow + (po + kw) * KVOX + q * 32 + kq * 8);
                    acc = __builtin_amdgcn_mfma_f32_16x16x32_f16(a, b, acc, 0, 0, 0);
                }
            }
        }
    }

    int pos = ((z0 + zw) * 32 + (y0 + yw)) * 32 + x0 + po;
    #pragma unroll
    for (int r = 0; r < 4; ++r)
        out[(size_t)(kq * 4 + r) * LTOT + pos] = acc[r];
}

// ---------------- Fallback: fully fused (no workspace needed) ---------------
__global__ __launch_bounds__(64) void fused_kernel(const float* __restrict__ x,
                                                   const float* __restrict__ bw,
                                                   const float* __restrict__ sw,
                                                   const float* __restrict__ sc,
                                                   float* __restrict__ out) {
    int p = blockIdx.x * 64 + threadIdx.x;
    int xo = p & 31;
    int yo = (p >> 5) & 31;
    int zo = p >> 10;
    float acc[OUT_CH];
    #pragma unroll
    for (int o = 0; o < OUT_CH; ++o) acc[o] = 0.0f;
    for (int c = 0; c < IN_CH; ++c)
        for (int kd = 0; kd < 3; ++kd)
            for (int kh = 0; kh < 3; ++kh)
                for (int kw = 0; kw < 3; ++kw) {
                    int zi = zo + kd - 1, yi = yo + kh - 1, xi = xo + kw - 1;
                    float v = 0.0f;
                    if (zi >= 0 && zi < DIM && yi >= 0 && yi < DIM && xi >= 0 && xi < DIM)
                        v = x[((c * DIM + zi) * DIM + yi) * DIM + xi];
                    float b[11];
                    eval_bases(v, b);
                    float s = silu(v);
                    int i = c * 27 + kd * 9 + kh * 3 + kw;
                    #pragma unroll
                    for (int o = 0; o < OUT_CH; ++o) {
                        int wi = o * NF + i;
                        float dot = 0.0f;
                        #pragma unroll
                        for (int j = 0; j < NBASES; ++j)
                            dot += b[j] * sw[(size_t)wi * NBASES + j];
                        acc[o] += s * bw[wi] + sc[wi] * dot;
                    }
                }
    #pragma unroll
    for (int o = 0; o < OUT_CH; ++o)
        out[(size_t)o * LTOT + p] = acc[o];
}

extern "C" void kernel_launch(void* const* d_in, const int* in_sizes, int n_in,
                              void* d_out, int out_size, void* d_ws, size_t ws_size,
                              hipStream_t stream) {
    const float* x  = (const float*)d_in[0];
    const float* bw = (const float*)d_in[1];
    const float* sw = (const float*)d_in[2];
    const float* sc = (const float*)d_in[3];
    float* out = (float*)d_out;

    const size_t W_bytes = (size_t)27 * 3 * 16 * 32 * 2;      // 82,944
    if (ws_size >= W_bytes) {
        _Float16* Wt = (_Float16*)d_ws;
        prep_weights<<<(27 * 3 * 16 * 32 + 255) / 256, 256, 0, stream>>>(bw, sw, sc, Wt);
        conv_fused<<<512, 256, 0, stream>>>(x, Wt, out);
    } else {
        fused_kernel<<<512, 64, 0, stream>>>(x, bw, sw, sc, out);
    }
}

// Round 6
// 77.649 us; speedup vs baseline: 1.2240x; 1.0098x over previous
//
#include <hip/hip_runtime.h>
#include <math.h>

// Problem constants (fixed shapes from reference)
#define IN_CH   8
#define OUT_CH  16
#define DIM     32
#define PDIM    34          // padded (pad=1 each side)
#define NBASES  8           // GRID_SIZE + SPLINE_ORDER
#define NF      216         // IN_CH * 27
#define LTOT    32768       // 32^3
#define TPAD    12          // 9 real values (silu + 8 bases) padded to 12
#define KVOX    96          // 8 channels * TPAD halves per voxel

typedef _Float16 half8 __attribute__((ext_vector_type(8)));
typedef float    f32x4 __attribute__((ext_vector_type(4)));

// knot j of the (uniform) extended grid: (j-3)*h + lo, h=0.4, lo=-1
__device__ __forceinline__ float knot(int j) {
    return (float)(j - 3) * 0.4f + (-1.0f);
}

// Cox-de Boor recursion (kept for the no-workspace fallback only).
__device__ __forceinline__ void eval_bases(float v, float b[11]) {
    #pragma unroll
    for (int j = 0; j < 11; ++j)
        b[j] = (v >= knot(j) && v < knot(j + 1)) ? 1.0f : 0.0f;
    #pragma unroll
    for (int k = 1; k <= 3; ++k) {
        #pragma unroll
        for (int j = 0; j + k < 11; ++j) {
            float rl = 1.0f / (knot(j + k)     - knot(j));      // const-folded
            float rr = 1.0f / (knot(j + k + 1) - knot(j + 1));  // const-folded
            b[j] = (v - knot(j)) * rl * b[j]
                 + (knot(j + k + 1) - v) * rr * b[j + 1];
        }
    }
}

// ---- Stage 1b: weights Wt[(tap*3+q)*16 + o][32] fp16 ----------------------
// k = q*32 + kl (0..95), c = k/12, t = k%12; t==0 -> base, 1..8 -> spline*scaler.
// Slots t=9..11 are ZERO — the conv kernel's LDS scatter relies on this to
// dump out-of-range spline pieces into slot 9 harmlessly.
__global__ void prep_weights(const float* __restrict__ bw,   // [16][216]
                             const float* __restrict__ sw,   // [16][216][8]
                             const float* __restrict__ sc,   // [16][216]
                             _Float16* __restrict__ Wt) {
    int id = blockIdx.x * blockDim.x + threadIdx.x;
    if (id >= 27 * 3 * 16 * 32) return;
    int kl  = id & 31;
    int o   = (id >> 5) & 15;
    int tq  = id >> 9;          // tap*3 + q
    int q   = tq % 3;
    int tap = tq / 3;
    int k = q * 32 + kl;        // 0..95
    int cch = k / TPAD, t = k % TPAD;
    float val = 0.0f;
    if (t < 9) {
        int wi = o * NF + (cch * 27 + tap);
        val = (t == 0) ? bw[wi] : sw[(size_t)wi * NBASES + (t - 1)] * sc[wi];
    }
    Wt[id] = (_Float16)val;
}

// Closed-form uniform cubic B-spline staging for one (voxel, channel):
// only 4 bases are nonzero: slots cj-3..cj with cardinal pieces
// {(1-u)^3, 4-6u^2+3u^3, 1+3u+3u^2-3u^3, u^3}/6. Out-of-range slots are
// redirected to pad slot 9 (weight there is zero). Verified equal to the
// truncated Cox-de-Boor recursion at interior, edges, and knot points.
__device__ __forceinline__ void stage_one(_Float16* __restrict__ rec, float val) {
    // silu via exp + hw reciprocal (1-ulp, far below fp16 noise)
    float s = val * __builtin_amdgcn_rcpf(1.0f + __expf(-val));
    // zero the 12-half record, silu in slot 0  (rec is 8B-aligned: 24B stride)
    union { _Float16 h[4]; uint2 q; } w0;
    w0.h[0] = (_Float16)s; w0.h[1] = (_Float16)0.f;
    w0.h[2] = (_Float16)0.f; w0.h[3] = (_Float16)0.f;
    uint2* r64 = (uint2*)rec;
    r64[0] = w0.q;
    r64[1] = make_uint2(0u, 0u);
    r64[2] = make_uint2(0u, 0u);
    // cell + local coordinate
    float cf = (val + 2.2f) * 2.5f;
    cf = fminf(fmaxf(cf, -1.0f), 12.0f);
    float fj = floorf(cf);
    int   cj = (int)fj;
    float u  = cf - fj;
    float um = 1.0f - u;
    float u2 = u * u, u3 = u2 * u;
    float q0 = u3 * (1.0f / 6.0f);                                  // j = cj
    float q1 = (1.0f + 3.0f * u + 3.0f * u2 - 3.0f * u3) * (1.0f / 6.0f);
    float q2 = (4.0f - 6.0f * u2 + 3.0f * u3) * (1.0f / 6.0f);
    float q3 = um * um * um * (1.0f / 6.0f);                        // j = cj-3
    int j0 = cj - 3;
    int t0 = ((unsigned)(j0    ) <= 7u) ? (j0 + 1) : 9;
    int t1 = ((unsigned)(j0 + 1) <= 7u) ? (j0 + 2) : 9;
    int t2 = ((unsigned)(j0 + 2) <= 7u) ? (j0 + 3) : 9;
    int t3 = ((unsigned)(j0 + 3) <= 7u) ? (j0 + 4) : 9;
    rec[t0] = (_Float16)q3;   // same-lane DS ops execute in order: after zeroing
    rec[t1] = (_Float16)q2;
    rec[t2] = (_Float16)q1;
    rec[t3] = (_Float16)q0;
}

// ---- Fused conv: compute halo spline-field into LDS, then implicit-GEMM ----
// Block: 256 thr = 4 waves. Output tile: 16(x) x 2(y) x 2(z) positions.
// LDS: halo field 18 x 4 x 4 voxels * 8ch * 12 halves = 55,296 B (2 blk/CU).
__global__ __launch_bounds__(256) void conv_fused(const float* __restrict__ x,
                                                  const _Float16* __restrict__ Wt,
                                                  float* __restrict__ out) {
    __shared__ __align__(16) _Float16 lf[288 * KVOX];   // 27648 halves
    int bx = blockIdx.x;
    int x0 = (bx & 1) * 16;
    int y0 = ((bx >> 1) & 15) * 2;
    int z0 = (bx >> 5) * 2;
    int tid = threadIdx.x;

    // ---- staging: 288 voxels x 8 ch; pass A: v=tid (0..255) x 8 channels,
    //      pass B: 32 leftover voxels x 8 channels. No integer div/mod in
    //      the hot path; guard + coords loop-invariant.
    {
        int v   = tid;               // voxel index (lz*4+ly)*18+lx
        int lx  = v % 18;
        int row = v / 18;
        int ly = row & 3, lz = row >> 2;
        int xp = x0 + lx, yp = y0 + ly, zp = z0 + lz;   // padded coords
        bool inr = (xp >= 1 && xp <= DIM && yp >= 1 && yp <= DIM && zp >= 1 && zp <= DIM);
        int gbase = (((zp - 1) * DIM + (yp - 1)) * DIM) + (xp - 1);
        float vals[IN_CH];
        #pragma unroll
        for (int c = 0; c < IN_CH; ++c)
            vals[c] = inr ? x[gbase + c * (DIM * DIM * DIM)] : 0.0f;
        #pragma unroll
        for (int c = 0; c < IN_CH; ++c)
            stage_one(lf + (size_t)v * KVOX + c * TPAD, vals[c]);

        // pass B: c2 = tid>>5 (0..7), v2 = 256 + (tid&31) (256..287)
        int c2  = tid >> 5;
        int v2  = 256 + (tid & 31);
        int lx2 = v2 % 18;
        int row2 = v2 / 18;
        int ly2 = row2 & 3, lz2 = row2 >> 2;
        int xp2 = x0 + lx2, yp2 = y0 + ly2, zp2 = z0 + lz2;
        bool inr2 = (xp2 >= 1 && xp2 <= DIM && yp2 >= 1 && yp2 <= DIM && zp2 >= 1 && zp2 <= DIM);
        float v2val = inr2 ? x[(((c2 * DIM + (zp2 - 1)) * DIM + (yp2 - 1)) * DIM) + (xp2 - 1)] : 0.0f;
        stage_one(lf + (size_t)v2 * KVOX + c2 * TPAD, v2val);
    }
    __syncthreads();

    // ---- MFMA phase (identical to verified R3/R5 layout) -------------------
    int lane = tid & 63;
    int w    = tid >> 6;
    int yw = w & 1, zw = w >> 1;
    int po = lane & 15;      // a: out-channel row; b: position col
    int kq = lane >> 4;      // K sub-chunk (8 halves each)
    f32x4 acc = {0.f, 0.f, 0.f, 0.f};

    #pragma unroll
    for (int kd = 0; kd < 3; ++kd) {
        #pragma unroll
        for (int kh = 0; kh < 3; ++kh) {
            const _Float16* lrow = lf + ((zw + kd) * 4 + (yw + kh)) * (18 * KVOX);
            #pragma unroll
            for (int kw = 0; kw < 3; ++kw) {
                #pragma unroll
                for (int q = 0; q < 3; ++q) {
                    int tap = (kd * 3 + kh) * 3 + kw;
                    half8 a = *(const half8*)(Wt + ((tap * 3 + q) * 16 + po) * 32 + kq * 8);
                    half8 b = *(const half8*)(lrow + (po + kw) * KVOX + q * 32 + kq * 8);
                    acc = __builtin_amdgcn_mfma_f32_16x16x32_f16(a, b, acc, 0, 0, 0);
                }
            }
        }
    }

    int pos = ((z0 + zw) * 32 + (y0 + yw)) * 32 + x0 + po;
    #pragma unroll
    for (int r = 0; r < 4; ++r)
        out[(size_t)(kq * 4 + r) * LTOT + pos] = acc[r];
}

// ---------------- Fallback: fully fused (no workspace needed) ---------------
__global__ __launch_bounds__(64) void fused_kernel(const float* __restrict__ x,
                                                   const float* __restrict__ bw,
                                                   const float* __restrict__ sw,
                                                   const float* __restrict__ sc,
                                                   float* __restrict__ out) {
    int p = blockIdx.x * 64 + threadIdx.x;
    int xo = p & 31;
    int yo = (p >> 5) & 31;
    int zo = p >> 10;
    float acc[OUT_CH];
    #pragma unroll
    for (int o = 0; o < OUT_CH; ++o) acc[o] = 0.0f;
    for (int c = 0; c < IN_CH; ++c)
        for (int kd = 0; kd < 3; ++kd)
            for (int kh = 0; kh < 3; ++kh)
                for (int kw = 0; kw < 3; ++kw) {
                    int zi = zo + kd - 1, yi = yo + kh - 1, xi = xo + kw - 1;
                    float v = 0.0f;
                    if (zi >= 0 && zi < DIM && yi >= 0 && yi < DIM && xi >= 0 && xi < DIM)
                        v = x[((c * DIM + zi) * DIM + yi) * DIM + xi];
                    float b[11];
                    eval_bases(v, b);
                    float s = v * __builtin_amdgcn_rcpf(1.0f + __expf(-v));
                    int i = c * 27 + kd * 9 + kh * 3 + kw;
                    #pragma unroll
                    for (int o = 0; o < OUT_CH; ++o) {
                        int wi = o * NF + i;
                        float dot = 0.0f;
                        #pragma unroll
                        for (int j = 0; j < NBASES; ++j)
                            dot += b[j] * sw[(size_t)wi * NBASES + j];
                        acc[o] += s * bw[wi] + sc[wi] * dot;
                    }
                }
    #pragma unroll
    for (int o = 0; o < OUT_CH; ++o)
        out[(size_t)o * LTOT + p] = acc[o];
}

extern "C" void kernel_launch(void* const* d_in, const int* in_sizes, int n_in,
                              void* d_out, int out_size, void* d_ws, size_t ws_size,
                              hipStream_t stream) {
    const float* x  = (const float*)d_in[0];
    const float* bw = (const float*)d_in[1];
    const float* sw = (const float*)d_in[2];
    const float* sc = (const float*)d_in[3];
    float* out = (float*)d_out;

    const size_t W_bytes = (size_t)27 * 3 * 16 * 32 * 2;      // 82,944
    if (ws_size >= W_bytes) {
        _Float16* Wt = (_Float16*)d_ws;
        prep_weights<<<(27 * 3 * 16 * 32 + 255) / 256, 256, 0, stream>>>(bw, sw, sc, Wt);
        conv_fused<<<512, 256, 0, stream>>>(x, Wt, out);
    } else {
        fused_kernel<<<512, 64, 0, stream>>>(x, bw, sw, sc, out);
    }
}